// Round 1
// baseline (221.722 us; speedup 1.0000x reference)
//
#include <hip/hip_runtime.h>
#include <hip/hip_bf16.h>

#define NB 32
#define DIN 512
#define TT 4096
#define DH 500
#define DHP 512
#define EPSV 1e-12f
#define BM 64
#define LDA 520  // bf16 elements, padded (+8) for bank-conflict-free b128

typedef short short8 __attribute__((ext_vector_type(8)));
typedef float f32x16 __attribute__((ext_vector_type(16)));
typedef float f32x4 __attribute__((ext_vector_type(4)));

__device__ inline unsigned short f2bf(float f) {
    unsigned int u = __builtin_bit_cast(unsigned int, f);
    unsigned int r = (u + 0x7fffu + ((u >> 16) & 1u)) >> 16;
    return (unsigned short)r;
}

// Kernel 0: convert/pad w1 -> bf16 [512][512], w2 -> f32 [512]
__global__ void prep_kernel(const float* __restrict__ w1, const float* __restrict__ w2,
                            unsigned short* __restrict__ w1b, float* __restrict__ w2f) {
    int idx = blockIdx.x * blockDim.x + threadIdx.x;
    if (idx < DHP * DIN) {
        int h = idx >> 9;
        int d = idx & 511;
        float v = (h < DH) ? w1[h * DIN + d] : 0.f;
        w1b[idx] = f2bf(v);
        if (idx < DHP) w2f[idx] = (idx < DH) ? w2[idx] : 0.f;
    }
}

// Kernel 1: scores[b][t] = sum_h w2[h] * relu(sum_d x[b,d,t] * w1[h,d])
// One block per (b, 64-t tile). 4 waves. Full N=512 looped in 4 chunks of 128
// (each wave owns 32 h-cols per chunk). A (x-tile, transposed to [t][d] bf16)
// staged once in LDS for all K=512.
__launch_bounds__(256, 2)
__global__ void scores_kernel(const float* __restrict__ x,
                              const unsigned short* __restrict__ w1b,
                              const float* __restrict__ w2f,
                              float* __restrict__ scores) {
    __shared__ unsigned short A_lds[BM][LDA];
    __shared__ float score_lds[BM];

    const int tid = threadIdx.x;
    const int lane = tid & 63;
    const int w = tid >> 6;
    const int bid = blockIdx.x;
    const int b = bid >> 6;            // 64 t-tiles per b
    const int t0 = (bid & 63) * BM;

    if (tid < BM) score_lds[tid] = 0.f;

    // ---- Stage A: x[b, d, t0+lane] -> A_lds[lane][d] (bf16) ----
    // wave w handles d-octets [w*128, w*128+128). Global loads coalesced over t.
    const float* xb = x + (size_t)b * DIN * TT + t0;
    #pragma unroll 4
    for (int i = 0; i < 16; ++i) {
        int d0 = (w * 16 + i) * 8;
        short8 pk;
        #pragma unroll
        for (int j = 0; j < 8; ++j) {
            float v = xb[(size_t)(d0 + j) * TT + lane];
            pk[j] = (short)f2bf(v);
        }
        *reinterpret_cast<short8*>(&A_lds[lane][d0]) = pk;
    }
    __syncthreads();

    // ---- MFMA main loop ----
    const int lane31 = lane & 31;
    const int khalf = lane >> 5;   // 0/1: which 8 of the K=16 slice
    float part[2][16];
    #pragma unroll
    for (int r = 0; r < 2; ++r)
        #pragma unroll
        for (int g = 0; g < 16; ++g) part[r][g] = 0.f;

    for (int nc = 0; nc < 4; ++nc) {
        const int hcol = nc * 128 + w * 32 + lane31;
        f32x16 acc0, acc1;
        #pragma unroll
        for (int g = 0; g < 16; ++g) { acc0[g] = 0.f; acc1[g] = 0.f; }

        const unsigned short* Bp = w1b + (size_t)hcol * DIN + khalf * 8;
        const unsigned short* Arow0 = &A_lds[lane31][khalf * 8];
        const unsigned short* Arow1 = &A_lds[32 + lane31][khalf * 8];

        #pragma unroll 4
        for (int ks = 0; ks < 32; ++ks) {
            const int k0 = ks * 16;
            short8 a0 = *reinterpret_cast<const short8*>(Arow0 + k0);
            short8 a1 = *reinterpret_cast<const short8*>(Arow1 + k0);
            short8 bb = *reinterpret_cast<const short8*>(Bp + k0);
            acc0 = __builtin_amdgcn_mfma_f32_32x32x16_bf16(a0, bb, acc0, 0, 0, 0);
            acc1 = __builtin_amdgcn_mfma_f32_32x32x16_bf16(a1, bb, acc1, 0, 0, 0);
        }
        const float wv2 = w2f[hcol];
        #pragma unroll
        for (int g = 0; g < 16; ++g) {
            part[0][g] += fmaxf(acc0[g], 0.f) * wv2;
            part[1][g] += fmaxf(acc1[g], 0.f) * wv2;
        }
    }

    // ---- reduce over h (cols live on lane&31) ----
    #pragma unroll
    for (int r = 0; r < 2; ++r) {
        #pragma unroll
        for (int g = 0; g < 16; ++g) {
            float v = part[r][g];
            #pragma unroll
            for (int m = 1; m <= 16; m <<= 1) v += __shfl_xor(v, m, 64);
            if (lane31 == 0) {
                int row = 32 * r + (g & 3) + 8 * (g >> 2) + 4 * khalf;
                atomicAdd(&score_lds[row], v);
            }
        }
    }
    __syncthreads();
    if (tid < BM) scores[(size_t)b * TT + t0 + tid] = score_lds[tid];
}

// Kernel 2: softmax over T per batch
__global__ void softmax_kernel(const float* __restrict__ scores, float* __restrict__ attn) {
    __shared__ float red[8];
    const int b = blockIdx.x;
    const int tid = threadIdx.x;
    const float* srow = scores + (size_t)b * TT;
    float v[16];
    float mx = -1e30f;
    #pragma unroll
    for (int j = 0; j < 16; ++j) { v[j] = srow[tid + 256 * j]; mx = fmaxf(mx, v[j]); }
    #pragma unroll
    for (int m = 1; m <= 32; m <<= 1) mx = fmaxf(mx, __shfl_xor(mx, m, 64));
    if ((tid & 63) == 0) red[tid >> 6] = mx;
    __syncthreads();
    mx = fmaxf(fmaxf(red[0], red[1]), fmaxf(red[2], red[3]));
    float sum = 0.f;
    #pragma unroll
    for (int j = 0; j < 16; ++j) { v[j] = __expf(v[j] - mx); sum += v[j]; }
    #pragma unroll
    for (int m = 1; m <= 32; m <<= 1) sum += __shfl_xor(sum, m, 64);
    if ((tid & 63) == 0) red[4 + (tid >> 6)] = sum;
    __syncthreads();
    sum = red[4] + red[5] + red[6] + red[7];
    const float inv = 1.f / sum;
    float* arow = attn + (size_t)b * TT;
    #pragma unroll
    for (int j = 0; j < 16; ++j) arow[tid + 256 * j] = v[j] * inv;
}

// Kernel 3: per (b,d): mean = sum_t x*attn; var = E[x^2]-2*mean*E[x]+mean^2
__global__ void stats_kernel(const float* __restrict__ x, const float* __restrict__ attn,
                             float* __restrict__ out) {
    const int w = threadIdx.x >> 6;
    const int lane = threadIdx.x & 63;
    const int row = blockIdx.x * 4 + w;      // b*512 + d
    const int b = row >> 9;
    const int d = row & 511;
    const float* xr = x + (size_t)row * TT;
    const float* ar = attn + (size_t)b * TT;
    float sx = 0.f, sx2 = 0.f, sxw = 0.f;
    #pragma unroll 4
    for (int i = 0; i < 16; ++i) {
        int t = (i * 64 + lane) * 4;
        f32x4 xv = *reinterpret_cast<const f32x4*>(xr + t);
        f32x4 av = *reinterpret_cast<const f32x4*>(ar + t);
        #pragma unroll
        for (int j = 0; j < 4; ++j) {
            float xx = xv[j];
            sx += xx; sx2 += xx * xx; sxw += xx * av[j];
        }
    }
    #pragma unroll
    for (int m = 1; m <= 32; m <<= 1) {
        sx  += __shfl_xor(sx, m, 64);
        sx2 += __shfl_xor(sx2, m, 64);
        sxw += __shfl_xor(sxw, m, 64);
    }
    if (lane == 0) {
        const float mean = sxw;
        const float ex = sx * (1.f / TT);
        const float ex2 = sx2 * (1.f / TT);
        float var = ex2 - 2.f * mean * ex + mean * mean;
        if (var <= EPSV) var = EPSV;
        out[(size_t)b * 1024 + d] = mean;
        out[(size_t)b * 1024 + 512 + d] = sqrtf(var);
    }
}

extern "C" void kernel_launch(void* const* d_in, const int* in_sizes, int n_in,
                              void* d_out, int out_size, void* d_ws, size_t ws_size,
                              hipStream_t stream) {
    const float* x  = (const float*)d_in[0];
    const float* w1 = (const float*)d_in[1];
    const float* w2 = (const float*)d_in[2];
    float* out = (float*)d_out;

    char* ws = (char*)d_ws;
    unsigned short* w1b = (unsigned short*)ws;                    // 512*512*2 = 512 KB
    float* w2f   = (float*)(ws + DHP * DIN * 2);                  // 2 KB
    float* scores = (float*)(ws + DHP * DIN * 2 + 2048);          // 512 KB
    float* attn   = scores + NB * TT;                             // 512 KB

    prep_kernel<<<(DHP * DIN + 255) / 256, 256, 0, stream>>>(w1, w2, w1b, w2f);
    scores_kernel<<<NB * (TT / BM), 256, 0, stream>>>(x, w1b, w2f, scores);
    softmax_kernel<<<NB, 256, 0, stream>>>(scores, attn);
    stats_kernel<<<NB * DIN / 4, 256, 0, stream>>>(x, attn, out);
}